// Round 5
// baseline (5722.154 us; speedup 1.0000x reference)
//
#include <hip/hip_runtime.h>
#include <hip/hip_bf16.h>
#include <hip/hip_fp16.h>

// TinyTransformerBlock: B=4, S=2048, D=1024, DFF=4096, fp32 in/out.
// R5: K-split waves. Block 128x128, BK=64, 4 waves; each wave computes the
// FULL 128-row x 64-col half-tile for ONE 32-wide k-half (wid&1), doubling
// wave MN-area -> LDS fragment traffic per FLOP drops 64->48 KB/block-iter
// (A read 2x, B read 1x). Epilogue: cross-wave partial reduction through LDS
// (bank-swizzled), then each wave stores a 64x64 final tile.
// XOR-swizzled staging layout (R4) retained: zero bank conflicts.

typedef _Float16 f16;
typedef __attribute__((ext_vector_type(8))) _Float16 f16x8;
typedef __attribute__((ext_vector_type(4))) _Float16 f16x4;
typedef __attribute__((ext_vector_type(4))) float f32x4;

#define BM 128
#define BN 128
#define BK 64

__device__ inline void gload16(const void* g, void* l) {
    __builtin_amdgcn_global_load_lds(
        (const __attribute__((address_space(1))) void*)g,
        (__attribute__((address_space(3))) void*)l, 16, 0, 0);
}

// EPI: 0 = f16 store, 1 = f16 relu store, 2 = f32 store, 3 = f32 + residual
// Grid: x = M-tile (fastest -> XCD-pinned A rows), y = N-tile, z = batch.
template<int EPI>
__global__ __launch_bounds__(256, 2)
void gemm_f16(const f16* __restrict__ A, const f16* __restrict__ Bt,
              const float* __restrict__ Res, void* __restrict__ Cv,
              int K, int lda, int ldb, int ldc,
              long long sA, long long sB, long long sC)
{
    __shared__ char smem[32 * 1024];
    f16* Ash = (f16*)smem;              // 16 KB staging A
    f16* Bsh = (f16*)(smem + 16384);    // 16 KB staging B
    float* xbuf = (float*)smem;         // epilogue exchange (aliases staging)

    const int t = threadIdx.x;
    const int z = blockIdx.z;
    A  += (size_t)z * sA;
    Bt += (size_t)z * sB;

    const int bm0 = blockIdx.x * BM;   // M-tile fastest
    const int bn0 = blockIdx.y * BN;

    const int lane = t & 63;
    const int wid  = t >> 6;            // wave 0..3
    const int quad = lane >> 4;
    const int m16  = lane & 15;
    const int ks   = wid & 1;           // k-half: 0 -> k 0..31, 1 -> k 32..63
    const int wn64 = (wid >> 1) * 64;   // N-half

    // staging: chunk c = i*256 + t -> LDS row r = c>>3 (128 B rows), half-slot
    // t&7. Source k-half XOR-swizzled: kc = ((t&7) ^ (r&7)) * 8 f16.
    const int r0 = t >> 3;              // 0..31
    const int kc = ((t & 7) ^ (r0 & 7)) * 8;
    const char* gA[4]; const char* gB[4];
    #pragma unroll
    for (int i = 0; i < 4; ++i) {
        gA[i] = (const char*)(A  + (size_t)(bm0 + i * 32 + r0) * lda + kc);
        gB[i] = (const char*)(Bt + (size_t)(bn0 + i * 32 + r0) * ldb + kc);
    }
    char* lA = (char*)Ash + (wid << 10);   // wave-uniform base (+ lane*16 by HW)
    char* lB = (char*)Bsh + (wid << 10);

    f32x4 acc[8][4] = {};   // 128 rows x 64 cols partial (this wave's k-half)

    const int nk = K / BK;
    #define ISSUE(kt) do { const int ko = (kt) * 128;   \
        gload16(gA[0] + ko, lA);                        \
        gload16(gA[1] + ko, lA + 4096);                 \
        gload16(gA[2] + ko, lA + 8192);                 \
        gload16(gA[3] + ko, lA + 12288);                \
        gload16(gB[0] + ko, lB);                        \
        gload16(gB[1] + ko, lB + 4096);                 \
        gload16(gB[2] + ko, lB + 8192);                 \
        gload16(gB[3] + ko, lB + 12288); } while (0)

    const int swz = m16 & 7;
    const int ha  = ((ks * 4 + quad) ^ swz) * 8;   // swizzled k-chunk offset

    ISSUE(0);
    for (int kt = 0; kt < nk; ++kt) {
        __syncthreads();                       // tile kt resident (vmcnt drained)
        f16x8 af[8], bf[4];
        #pragma unroll
        for (int i = 0; i < 8; ++i)
            af[i] = *(const f16x8*)&Ash[(i * 16 + m16) * BK + ha];
        #pragma unroll
        for (int j = 0; j < 4; ++j)
            bf[j] = *(const f16x8*)&Bsh[(wn64 + j * 16 + m16) * BK + ha];
        __syncthreads();                       // all waves' ds_reads done
        if (kt + 1 < nk) ISSUE(kt + 1);        // prefetch overlaps MFMA
        #pragma unroll
        for (int i = 0; i < 8; ++i)
            #pragma unroll
            for (int j = 0; j < 4; ++j)
                acc[i][j] = __builtin_amdgcn_mfma_f32_16x16x32_f16(
                                af[i], bf[j], acc[i][j], 0, 0, 0);
    }
    #undef ISSUE

    // ---- cross-wave k-half reduction through LDS ----
    // Pair (2p, 2p+1) share output cols wn64. ks=0 keeps rows 0-63,
    // ks=1 keeps rows 64-127. Exchange layout [64][64] f32, col XOR-swizzled
    // by bit2 of row (quad parity) -> 2-way max (free).
    float* xb = xbuf + (wid >> 1) * 4096;   // 16 KB per pair
    #define XIDX(row, col) ((row) * 64 + ((col) ^ (((row) & 4) << 2)))
    // phase 1: ks=1 writes rows 0-63 partials; ks=0 adds
    if (ks == 1) {
        #pragma unroll
        for (int i = 0; i < 4; ++i)
            #pragma unroll
            for (int j = 0; j < 4; ++j)
                #pragma unroll
                for (int ri = 0; ri < 4; ++ri)
                    xb[XIDX(i * 16 + quad * 4 + ri, j * 16 + m16)] = acc[i][j][ri];
    }
    __syncthreads();
    if (ks == 0) {
        #pragma unroll
        for (int i = 0; i < 4; ++i)
            #pragma unroll
            for (int j = 0; j < 4; ++j)
                #pragma unroll
                for (int ri = 0; ri < 4; ++ri)
                    acc[i][j][ri] += xb[XIDX(i * 16 + quad * 4 + ri, j * 16 + m16)];
    }
    __syncthreads();
    // phase 2: ks=0 writes rows 64-127 partials; ks=1 adds
    if (ks == 0) {
        #pragma unroll
        for (int i = 0; i < 4; ++i)
            #pragma unroll
            for (int j = 0; j < 4; ++j)
                #pragma unroll
                for (int ri = 0; ri < 4; ++ri)
                    xb[XIDX(i * 16 + quad * 4 + ri, j * 16 + m16)] = acc[i + 4][j][ri];
    }
    __syncthreads();
    if (ks == 1) {
        #pragma unroll
        for (int i = 0; i < 4; ++i)
            #pragma unroll
            for (int j = 0; j < 4; ++j)
                #pragma unroll
                for (int ri = 0; ri < 4; ++ri)
                    acc[i + 4][j][ri] += xb[XIDX(i * 16 + quad * 4 + ri, j * 16 + m16)];
    }
    #undef XIDX

    // ---- store: wave owns rows ks*64 .. ks*64+63, cols wn64 .. wn64+63 ----
    const int ib = ks * 4;
    if (EPI <= 1) {
        f16* C = (f16*)Cv + (size_t)z * sC;
        #pragma unroll
        for (int i = 0; i < 4; ++i)
            #pragma unroll
            for (int ri = 0; ri < 4; ++ri) {
                const size_t row = (size_t)(bm0 + ks * 64 + i * 16 + quad * 4 + ri);
                f16* cp = C + row * ldc + (bn0 + wn64 + m16);
                #pragma unroll
                for (int j = 0; j < 4; ++j) {
                    float v = acc[ib + i][j][ri];
                    if (EPI == 1) v = fmaxf(v, 0.0f);
                    cp[j * 16] = (f16)v;
                }
            }
    } else {
        float* C = (float*)Cv + (size_t)z * sC;
        #pragma unroll
        for (int i = 0; i < 4; ++i)
            #pragma unroll
            for (int ri = 0; ri < 4; ++ri) {
                const size_t row = (size_t)(bm0 + ks * 64 + i * 16 + quad * 4 + ri);
                float* cp = C + row * ldc + (bn0 + wn64 + m16);
                const float* rp = (EPI == 3) ? Res + row * ldc + (bn0 + wn64 + m16)
                                             : nullptr;
                #pragma unroll
                for (int j = 0; j < 4; ++j) {
                    float v = acc[ib + i][j][ri];
                    if (EPI == 3) v += rp[j * 16];
                    cp[j * 16] = v;
                }
            }
    }
}

// fp32 [R][C] -> fp16 [C][R], 4 sources (z selects), all R=C=1024
__global__ __launch_bounds__(256)
void transpose_cast4(const float* __restrict__ s0, const float* __restrict__ s1,
                     const float* __restrict__ s2, const float* __restrict__ s3,
                     f16* __restrict__ d0, f16* __restrict__ d1,
                     f16* __restrict__ d2, f16* __restrict__ d3)
{
    const int R = 1024, C = 1024;
    const int z = blockIdx.z;
    const float* in = (z == 0) ? s0 : (z == 1) ? s1 : (z == 2) ? s2 : s3;
    f16* out = (z == 0) ? d0 : (z == 1) ? d1 : (z == 2) ? d2 : d3;
    __shared__ float tile[64][65];
    const int c0 = blockIdx.x * 64, r0 = blockIdx.y * 64;
    const int tc = threadIdx.x & 63, tr = threadIdx.x >> 6;
    #pragma unroll
    for (int i = 0; i < 16; ++i)
        tile[tr + i * 4][tc] = in[(size_t)(r0 + tr + i * 4) * C + c0 + tc];
    __syncthreads();
    #pragma unroll
    for (int i = 0; i < 16; ++i)
        out[(size_t)(c0 + tr + i * 4) * R + r0 + tc] = (f16)tile[tc][tr + i * 4];
}

// fp32 [R][C] -> fp16 [C][R]
__global__ __launch_bounds__(256)
void transpose_cast(const float* __restrict__ in, f16* __restrict__ out,
                    int R, int C)
{
    __shared__ float tile[64][65];
    const int c0 = blockIdx.x * 64, r0 = blockIdx.y * 64;
    const int tc = threadIdx.x & 63, tr = threadIdx.x >> 6;
    #pragma unroll
    for (int i = 0; i < 16; ++i)
        tile[tr + i * 4][tc] = in[(size_t)(r0 + tr + i * 4) * C + c0 + tc];
    __syncthreads();
    #pragma unroll
    for (int i = 0; i < 16; ++i)
        out[(size_t)(c0 + tr + i * 4) * R + r0 + tc] = (f16)tile[tc][tr + i * 4];
}

__global__ __launch_bounds__(256)
void cast_f16(const float* __restrict__ in, f16* __restrict__ out)
{
    const size_t i = ((size_t)blockIdx.x * 256 + threadIdx.x) * 4;
    float4 v = *(const float4*)(in + i);
    f16x4 o; o.x = (f16)v.x; o.y = (f16)v.y; o.z = (f16)v.z; o.w = (f16)v.w;
    *(f16x4*)(out + i) = o;
}

// row softmax over 2048 fp32 -> fp16
__global__ __launch_bounds__(256)
void softmax_f16(const float* __restrict__ S, f16* __restrict__ P)
{
    __shared__ float red[256];
    const float* p = S + (size_t)blockIdx.x * 2048;
    f16* q = P + (size_t)blockIdx.x * 2048;
    const int t = threadIdx.x;

    float4 u0 = *(const float4*)(p + t * 4);
    float4 u1 = *(const float4*)(p + 1024 + t * 4);

    float m = fmaxf(fmaxf(fmaxf(u0.x, u0.y), fmaxf(u0.z, u0.w)),
                    fmaxf(fmaxf(u1.x, u1.y), fmaxf(u1.z, u1.w)));
    red[t] = m;
    __syncthreads();
    #pragma unroll
    for (int s = 128; s > 0; s >>= 1) {
        if (t < s) red[t] = fmaxf(red[t], red[t + s]);
        __syncthreads();
    }
    const float rowmax = red[0];
    __syncthreads();

    u0.x = __expf(u0.x - rowmax); u0.y = __expf(u0.y - rowmax);
    u0.z = __expf(u0.z - rowmax); u0.w = __expf(u0.w - rowmax);
    u1.x = __expf(u1.x - rowmax); u1.y = __expf(u1.y - rowmax);
    u1.z = __expf(u1.z - rowmax); u1.w = __expf(u1.w - rowmax);

    red[t] = (u0.x + u0.y + u0.z + u0.w) + (u1.x + u1.y + u1.z + u1.w);
    __syncthreads();
    #pragma unroll
    for (int s = 128; s > 0; s >>= 1) {
        if (t < s) red[t] += red[t + s];
        __syncthreads();
    }
    const float inv = 1.0f / red[0];

    f16x4 o0, o1;
    o0.x = (f16)(u0.x * inv); o0.y = (f16)(u0.y * inv);
    o0.z = (f16)(u0.z * inv); o0.w = (f16)(u0.w * inv);
    o1.x = (f16)(u1.x * inv); o1.y = (f16)(u1.y * inv);
    o1.z = (f16)(u1.z * inv); o1.w = (f16)(u1.w * inv);
    *(f16x4*)(q + t * 4)        = o0;
    *(f16x4*)(q + 1024 + t * 4) = o1;
}

extern "C" void kernel_launch(void* const* d_in, const int* in_sizes, int n_in,
                              void* d_out, int out_size, void* d_ws, size_t ws_size,
                              hipStream_t stream)
{
    const float* x  = (const float*)d_in[0];
    const float* wq = (const float*)d_in[1];
    const float* wk = (const float*)d_in[2];
    const float* wv = (const float*)d_in[3];
    const float* wo = (const float*)d_in[4];
    const float* w1 = (const float*)d_in[5];
    const float* w2 = (const float*)d_in[6];
    float* out = (float*)d_out;

    const int S = 2048, D = 1024, DFF = 4096, Bb = 4;
    const int NTOK = Bb * S;  // 8192

    // workspace (halves unless noted); total 152 MB
    f16* W    = (f16*)d_ws;
    f16* xh   = W;                           // 8M
    f16* wqkT = xh   + (size_t)NTOK * D;     // 2M  ([2048][1024]: wqT | wkT)
    f16* wvT  = wqkT + (size_t)2 * D * D;    // 1M
    f16* woT  = wvT  + (size_t)D * D;        // 1M
    f16* w1T  = woT  + (size_t)D * D;        // 4M
    f16* w2T  = w1T  + (size_t)D * DFF;      // 4M
    f16* qk   = w2T  + (size_t)DFF * D;      // 16M ([8192][2048])
    f16* vT   = qk   + (size_t)NTOK * 2 * D; // 8M  ([1024][8192])
    float* sb = (float*)(vT + (size_t)D * NTOK);  // 16M fp32 (64 MB)
    f16* ph   = qk;                          // probs overwrite q|k (16M)
    f16* at   = xh;                          // attn overwrites xh
    f16* pj   = vT;                          // proj overwrites vT
    f16* hd   = (f16*)sb;                    // hidden overwrites scores

    dim3 blk(256);

    // casts / transposes
    cast_f16<<<dim3(NTOK * D / 1024), blk, 0, stream>>>(x, xh);
    transpose_cast4<<<dim3(D / 64, D / 64, 4), blk, 0, stream>>>(
        wq, wk, wv, wo, wqkT, wqkT + (size_t)D * D, wvT, woT);
    transpose_cast<<<dim3(DFF / 64, D / 64), blk, 0, stream>>>(w1, w1T, D, DFF);
    transpose_cast<<<dim3(D / 64, DFF / 64), blk, 0, stream>>>(w2, w2T, DFF, D);

    // qk = xh @ wqkT'   [8192][2048]
    gemm_f16<0><<<dim3(NTOK / BM, 2 * D / BN, 1), blk, 0, stream>>>(
        xh, wqkT, nullptr, qk, D, D, D, 2 * D, 0, 0, 0);
    // vT = wvT @ xh'    [1024][8192]
    gemm_f16<0><<<dim3(D / BM, NTOK / BN, 1), blk, 0, stream>>>(
        wvT, xh, nullptr, vT, D, D, D, NTOK, 0, 0, 0);

    // scores[b] = q_b @ k_b'  fp32 [2048][2048] x4
    gemm_f16<2><<<dim3(S / BM, S / BN, Bb), blk, 0, stream>>>(
        qk, qk + D, nullptr, sb, D, 2 * D, 2 * D, S,
        (long long)S * 2 * D, (long long)S * 2 * D, (long long)S * S);

    // softmax -> fp16 probs (overwrites qk)
    softmax_f16<<<dim3(NTOK), blk, 0, stream>>>(sb, ph);

    // attn[b] = p_b @ (vT[:, b-slice])'   [2048][1024] x4
    gemm_f16<0><<<dim3(S / BM, D / BN, Bb), blk, 0, stream>>>(
        ph, vT, nullptr, at, S, S, NTOK, D,
        (long long)S * S, (long long)S, (long long)S * D);

    // proj = at @ woT'
    gemm_f16<0><<<dim3(NTOK / BM, D / BN, 1), blk, 0, stream>>>(
        at, woT, nullptr, pj, D, D, D, D, 0, 0, 0);

    // hidden = relu(pj @ w1T')   [8192][4096]
    gemm_f16<1><<<dim3(NTOK / BM, DFF / BN, 1), blk, 0, stream>>>(
        pj, w1T, nullptr, hd, D, D, D, DFF, 0, 0, 0);

    // out = hd @ w2T' + x   fp32 [8192][1024]
    gemm_f16<3><<<dim3(NTOK / BM, D / BN, 1), blk, 0, stream>>>(
        hd, w2T, x, out, DFF, DFF, DFF, D, 0, 0, 0);
}

// Round 6
// 445.872 us; speedup vs baseline: 12.8336x; 12.8336x over previous
//
#include <hip/hip_runtime.h>
#include <hip/hip_bf16.h>
#include <hip/hip_fp16.h>

// TinyTransformerBlock: B=4, S=2048, D=1024, DFF=4096, fp32 in/out.
// R6 = R5 (K-split waves) with the scratch-spill bug fixed: the store epilogue
// previously indexed acc[ks*4 + i] (runtime index -> whole acc array demoted
// to scratch, VGPR=64, 7 GB of spill traffic, 12x regression). Now both arms
// branch on ks with compile-time acc indices.
//
// K-split: block 128x128, BK=64, 4 waves; wave = (k-half ks, N-half wn64),
// computes full 128-row x 64-col partial for its 32-wide k-half. LDS fragment
// traffic 64->48 KB per block-iter. Epilogue: cross-wave k-reduction via LDS
// (bank-swizzled), each wave stores a 64x64 final tile.
// XOR-swizzled staging (R4): zero bank conflicts.

typedef _Float16 f16;
typedef __attribute__((ext_vector_type(8))) _Float16 f16x8;
typedef __attribute__((ext_vector_type(4))) _Float16 f16x4;
typedef __attribute__((ext_vector_type(4))) float f32x4;

#define BM 128
#define BN 128
#define BK 64

__device__ inline void gload16(const void* g, void* l) {
    __builtin_amdgcn_global_load_lds(
        (const __attribute__((address_space(1))) void*)g,
        (__attribute__((address_space(3))) void*)l, 16, 0, 0);
}

// EPI: 0 = f16 store, 1 = f16 relu store, 2 = f32 store, 3 = f32 + residual
// Grid: x = M-tile (fastest -> XCD-pinned A rows), y = N-tile, z = batch.
template<int EPI>
__global__ __launch_bounds__(256, 2)
void gemm_f16(const f16* __restrict__ A, const f16* __restrict__ Bt,
              const float* __restrict__ Res, void* __restrict__ Cv,
              int K, int lda, int ldb, int ldc,
              long long sA, long long sB, long long sC)
{
    __shared__ char smem[32 * 1024];
    f16* Ash = (f16*)smem;              // 16 KB staging A
    f16* Bsh = (f16*)(smem + 16384);    // 16 KB staging B
    float* xbuf = (float*)smem;         // epilogue exchange (aliases staging)

    const int t = threadIdx.x;
    const int z = blockIdx.z;
    A  += (size_t)z * sA;
    Bt += (size_t)z * sB;

    const int bm0 = blockIdx.x * BM;   // M-tile fastest
    const int bn0 = blockIdx.y * BN;

    const int lane = t & 63;
    const int wid  = t >> 6;            // wave 0..3
    const int quad = lane >> 4;
    const int m16  = lane & 15;
    const int ks   = wid & 1;           // k-half: 0 -> k 0..31, 1 -> k 32..63
    const int wn64 = (wid >> 1) * 64;   // N-half

    // staging: chunk c = i*256 + t -> LDS row r = c>>3 (128 B rows), half-slot
    // t&7. Source k-half XOR-swizzled: kc = ((t&7) ^ (r&7)) * 8 f16.
    const int r0 = t >> 3;              // 0..31
    const int kc = ((t & 7) ^ (r0 & 7)) * 8;
    const char* gA[4]; const char* gB[4];
    #pragma unroll
    for (int i = 0; i < 4; ++i) {
        gA[i] = (const char*)(A  + (size_t)(bm0 + i * 32 + r0) * lda + kc);
        gB[i] = (const char*)(Bt + (size_t)(bn0 + i * 32 + r0) * ldb + kc);
    }
    char* lA = (char*)Ash + (wid << 10);   // wave-uniform base (+ lane*16 by HW)
    char* lB = (char*)Bsh + (wid << 10);

    f32x4 acc[8][4] = {};   // 128 rows x 64 cols partial (this wave's k-half)

    const int nk = K / BK;
    #define ISSUE(kt) do { const int ko = (kt) * 128;   \
        gload16(gA[0] + ko, lA);                        \
        gload16(gA[1] + ko, lA + 4096);                 \
        gload16(gA[2] + ko, lA + 8192);                 \
        gload16(gA[3] + ko, lA + 12288);                \
        gload16(gB[0] + ko, lB);                        \
        gload16(gB[1] + ko, lB + 4096);                 \
        gload16(gB[2] + ko, lB + 8192);                 \
        gload16(gB[3] + ko, lB + 12288); } while (0)

    const int swz = m16 & 7;
    const int ha  = ((ks * 4 + quad) ^ swz) * 8;   // swizzled k-chunk offset

    ISSUE(0);
    for (int kt = 0; kt < nk; ++kt) {
        __syncthreads();                       // tile kt resident (vmcnt drained)
        f16x8 af[8], bf[4];
        #pragma unroll
        for (int i = 0; i < 8; ++i)
            af[i] = *(const f16x8*)&Ash[(i * 16 + m16) * BK + ha];
        #pragma unroll
        for (int j = 0; j < 4; ++j)
            bf[j] = *(const f16x8*)&Bsh[(wn64 + j * 16 + m16) * BK + ha];
        __syncthreads();                       // all waves' ds_reads done
        if (kt + 1 < nk) ISSUE(kt + 1);        // prefetch overlaps MFMA
        #pragma unroll
        for (int i = 0; i < 8; ++i)
            #pragma unroll
            for (int j = 0; j < 4; ++j)
                acc[i][j] = __builtin_amdgcn_mfma_f32_16x16x32_f16(
                                af[i], bf[j], acc[i][j], 0, 0, 0);
    }
    #undef ISSUE

    // ---- cross-wave k-half reduction through LDS ----
    // Pair (2p, 2p+1) share output cols wn64. ks=0 keeps rows 0-63,
    // ks=1 keeps rows 64-127. Exchange layout [64][64] f32, col XOR-swizzled
    // by quad parity -> 2-way max (free). All acc indices compile-time.
    float* xb = xbuf + (wid >> 1) * 4096;   // 16 KB per pair
    #define XIDX(row, col) ((row) * 64 + ((col) ^ (((row) & 4) << 2)))
    if (ks == 1) {
        #pragma unroll
        for (int i = 0; i < 4; ++i)
            #pragma unroll
            for (int j = 0; j < 4; ++j)
                #pragma unroll
                for (int ri = 0; ri < 4; ++ri)
                    xb[XIDX(i * 16 + quad * 4 + ri, j * 16 + m16)] = acc[i][j][ri];
    }
    __syncthreads();
    if (ks == 0) {
        #pragma unroll
        for (int i = 0; i < 4; ++i)
            #pragma unroll
            for (int j = 0; j < 4; ++j)
                #pragma unroll
                for (int ri = 0; ri < 4; ++ri)
                    acc[i][j][ri] += xb[XIDX(i * 16 + quad * 4 + ri, j * 16 + m16)];
    }
    __syncthreads();
    if (ks == 0) {
        #pragma unroll
        for (int i = 0; i < 4; ++i)
            #pragma unroll
            for (int j = 0; j < 4; ++j)
                #pragma unroll
                for (int ri = 0; ri < 4; ++ri)
                    xb[XIDX(i * 16 + quad * 4 + ri, j * 16 + m16)] = acc[i + 4][j][ri];
    }
    __syncthreads();
    if (ks == 1) {
        #pragma unroll
        for (int i = 0; i < 4; ++i)
            #pragma unroll
            for (int j = 0; j < 4; ++j)
                #pragma unroll
                for (int ri = 0; ri < 4; ++ri)
                    acc[i + 4][j][ri] += xb[XIDX(i * 16 + quad * 4 + ri, j * 16 + m16)];
    }
    #undef XIDX

    // ---- store: wave owns rows ks*64..ks*64+63, cols wn64..wn64+63 ----
    // COMPILE-TIME acc indices in both arms (runtime index caused R5 spill).
    #define STORE_TILE(IB, RB)                                                  \
        do {                                                                    \
            if (EPI <= 1) {                                                     \
                f16* C = (f16*)Cv + (size_t)z * sC;                             \
                _Pragma("unroll")                                               \
                for (int i = 0; i < 4; ++i)                                     \
                    _Pragma("unroll")                                           \
                    for (int ri = 0; ri < 4; ++ri) {                            \
                        const size_t row = (size_t)(bm0 + (RB) + i * 16 + quad * 4 + ri); \
                        f16* cp = C + row * ldc + (bn0 + wn64 + m16);           \
                        _Pragma("unroll")                                       \
                        for (int j = 0; j < 4; ++j) {                           \
                            float v = acc[(IB) + i][j][ri];                     \
                            if (EPI == 1) v = fmaxf(v, 0.0f);                   \
                            cp[j * 16] = (f16)v;                                \
                        }                                                       \
                    }                                                           \
            } else {                                                            \
                float* C = (float*)Cv + (size_t)z * sC;                         \
                _Pragma("unroll")                                               \
                for (int i = 0; i < 4; ++i)                                     \
                    _Pragma("unroll")                                           \
                    for (int ri = 0; ri < 4; ++ri) {                            \
                        const size_t row = (size_t)(bm0 + (RB) + i * 16 + quad * 4 + ri); \
                        float* cp = C + row * ldc + (bn0 + wn64 + m16);         \
                        const float* rp = (EPI == 3)                            \
                            ? Res + row * ldc + (bn0 + wn64 + m16) : nullptr;   \
                        _Pragma("unroll")                                       \
                        for (int j = 0; j < 4; ++j) {                           \
                            float v = acc[(IB) + i][j][ri];                     \
                            if (EPI == 3) v += rp[j * 16];                      \
                            cp[j * 16] = v;                                     \
                        }                                                       \
                    }                                                           \
            }                                                                   \
        } while (0)

    if (ks == 0) STORE_TILE(0, 0);
    else         STORE_TILE(4, 64);
    #undef STORE_TILE
}

// fp32 [R][C] -> fp16 [C][R], 4 sources (z selects), all R=C=1024
__global__ __launch_bounds__(256)
void transpose_cast4(const float* __restrict__ s0, const float* __restrict__ s1,
                     const float* __restrict__ s2, const float* __restrict__ s3,
                     f16* __restrict__ d0, f16* __restrict__ d1,
                     f16* __restrict__ d2, f16* __restrict__ d3)
{
    const int R = 1024, C = 1024;
    const int z = blockIdx.z;
    const float* in = (z == 0) ? s0 : (z == 1) ? s1 : (z == 2) ? s2 : s3;
    f16* out = (z == 0) ? d0 : (z == 1) ? d1 : (z == 2) ? d2 : d3;
    __shared__ float tile[64][65];
    const int c0 = blockIdx.x * 64, r0 = blockIdx.y * 64;
    const int tc = threadIdx.x & 63, tr = threadIdx.x >> 6;
    #pragma unroll
    for (int i = 0; i < 16; ++i)
        tile[tr + i * 4][tc] = in[(size_t)(r0 + tr + i * 4) * C + c0 + tc];
    __syncthreads();
    #pragma unroll
    for (int i = 0; i < 16; ++i)
        out[(size_t)(c0 + tr + i * 4) * R + r0 + tc] = (f16)tile[tc][tr + i * 4];
}

// fp32 [R][C] -> fp16 [C][R]
__global__ __launch_bounds__(256)
void transpose_cast(const float* __restrict__ in, f16* __restrict__ out,
                    int R, int C)
{
    __shared__ float tile[64][65];
    const int c0 = blockIdx.x * 64, r0 = blockIdx.y * 64;
    const int tc = threadIdx.x & 63, tr = threadIdx.x >> 6;
    #pragma unroll
    for (int i = 0; i < 16; ++i)
        tile[tr + i * 4][tc] = in[(size_t)(r0 + tr + i * 4) * C + c0 + tc];
    __syncthreads();
    #pragma unroll
    for (int i = 0; i < 16; ++i)
        out[(size_t)(c0 + tr + i * 4) * R + r0 + tc] = (f16)tile[tc][tr + i * 4];
}

__global__ __launch_bounds__(256)
void cast_f16(const float* __restrict__ in, f16* __restrict__ out)
{
    const size_t i = ((size_t)blockIdx.x * 256 + threadIdx.x) * 4;
    float4 v = *(const float4*)(in + i);
    f16x4 o; o.x = (f16)v.x; o.y = (f16)v.y; o.z = (f16)v.z; o.w = (f16)v.w;
    *(f16x4*)(out + i) = o;
}

// row softmax over 2048 fp32 -> fp16
__global__ __launch_bounds__(256)
void softmax_f16(const float* __restrict__ S, f16* __restrict__ P)
{
    __shared__ float red[256];
    const float* p = S + (size_t)blockIdx.x * 2048;
    f16* q = P + (size_t)blockIdx.x * 2048;
    const int t = threadIdx.x;

    float4 u0 = *(const float4*)(p + t * 4);
    float4 u1 = *(const float4*)(p + 1024 + t * 4);

    float m = fmaxf(fmaxf(fmaxf(u0.x, u0.y), fmaxf(u0.z, u0.w)),
                    fmaxf(fmaxf(u1.x, u1.y), fmaxf(u1.z, u1.w)));
    red[t] = m;
    __syncthreads();
    #pragma unroll
    for (int s = 128; s > 0; s >>= 1) {
        if (t < s) red[t] = fmaxf(red[t], red[t + s]);
        __syncthreads();
    }
    const float rowmax = red[0];
    __syncthreads();

    u0.x = __expf(u0.x - rowmax); u0.y = __expf(u0.y - rowmax);
    u0.z = __expf(u0.z - rowmax); u0.w = __expf(u0.w - rowmax);
    u1.x = __expf(u1.x - rowmax); u1.y = __expf(u1.y - rowmax);
    u1.z = __expf(u1.z - rowmax); u1.w = __expf(u1.w - rowmax);

    red[t] = (u0.x + u0.y + u0.z + u0.w) + (u1.x + u1.y + u1.z + u1.w);
    __syncthreads();
    #pragma unroll
    for (int s = 128; s > 0; s >>= 1) {
        if (t < s) red[t] += red[t + s];
        __syncthreads();
    }
    const float inv = 1.0f / red[0];

    f16x4 o0, o1;
    o0.x = (f16)(u0.x * inv); o0.y = (f16)(u0.y * inv);
    o0.z = (f16)(u0.z * inv); o0.w = (f16)(u0.w * inv);
    o1.x = (f16)(u1.x * inv); o1.y = (f16)(u1.y * inv);
    o1.z = (f16)(u1.z * inv); o1.w = (f16)(u1.w * inv);
    *(f16x4*)(q + t * 4)        = o0;
    *(f16x4*)(q + 1024 + t * 4) = o1;
}

extern "C" void kernel_launch(void* const* d_in, const int* in_sizes, int n_in,
                              void* d_out, int out_size, void* d_ws, size_t ws_size,
                              hipStream_t stream)
{
    const float* x  = (const float*)d_in[0];
    const float* wq = (const float*)d_in[1];
    const float* wk = (const float*)d_in[2];
    const float* wv = (const float*)d_in[3];
    const float* wo = (const float*)d_in[4];
    const float* w1 = (const float*)d_in[5];
    const float* w2 = (const float*)d_in[6];
    float* out = (float*)d_out;

    const int S = 2048, D = 1024, DFF = 4096, Bb = 4;
    const int NTOK = Bb * S;  // 8192

    // workspace (halves unless noted); total 152 MB
    f16* W    = (f16*)d_ws;
    f16* xh   = W;                           // 8M
    f16* wqkT = xh   + (size_t)NTOK * D;     // 2M  ([2048][1024]: wqT | wkT)
    f16* wvT  = wqkT + (size_t)2 * D * D;    // 1M
    f16* woT  = wvT  + (size_t)D * D;        // 1M
    f16* w1T  = woT  + (size_t)D * D;        // 4M
    f16* w2T  = w1T  + (size_t)D * DFF;      // 4M
    f16* qk   = w2T  + (size_t)DFF * D;      // 16M ([8192][2048])
    f16* vT   = qk   + (size_t)NTOK * 2 * D; // 8M  ([1024][8192])
    float* sb = (float*)(vT + (size_t)D * NTOK);  // 16M fp32 (64 MB)
    f16* ph   = qk;                          // probs overwrite q|k (16M)
    f16* at   = xh;                          // attn overwrites xh
    f16* pj   = vT;                          // proj overwrites vT
    f16* hd   = (f16*)sb;                    // hidden overwrites scores

    dim3 blk(256);

    // casts / transposes
    cast_f16<<<dim3(NTOK * D / 1024), blk, 0, stream>>>(x, xh);
    transpose_cast4<<<dim3(D / 64, D / 64, 4), blk, 0, stream>>>(
        wq, wk, wv, wo, wqkT, wqkT + (size_t)D * D, wvT, woT);
    transpose_cast<<<dim3(DFF / 64, D / 64), blk, 0, stream>>>(w1, w1T, D, DFF);
    transpose_cast<<<dim3(D / 64, DFF / 64), blk, 0, stream>>>(w2, w2T, DFF, D);

    // qk = xh @ wqkT'   [8192][2048]
    gemm_f16<0><<<dim3(NTOK / BM, 2 * D / BN, 1), blk, 0, stream>>>(
        xh, wqkT, nullptr, qk, D, D, D, 2 * D, 0, 0, 0);
    // vT = wvT @ xh'    [1024][8192]
    gemm_f16<0><<<dim3(D / BM, NTOK / BN, 1), blk, 0, stream>>>(
        wvT, xh, nullptr, vT, D, D, D, NTOK, 0, 0, 0);

    // scores[b] = q_b @ k_b'  fp32 [2048][2048] x4
    gemm_f16<2><<<dim3(S / BM, S / BN, Bb), blk, 0, stream>>>(
        qk, qk + D, nullptr, sb, D, 2 * D, 2 * D, S,
        (long long)S * 2 * D, (long long)S * 2 * D, (long long)S * S);

    // softmax -> fp16 probs (overwrites qk)
    softmax_f16<<<dim3(NTOK), blk, 0, stream>>>(sb, ph);

    // attn[b] = p_b @ (vT[:, b-slice])'   [2048][1024] x4
    gemm_f16<0><<<dim3(S / BM, D / BN, Bb), blk, 0, stream>>>(
        ph, vT, nullptr, at, S, S, NTOK, D,
        (long long)S * S, (long long)S, (long long)S * D);

    // proj = at @ woT'
    gemm_f16<0><<<dim3(NTOK / BM, D / BN, 1), blk, 0, stream>>>(
        at, woT, nullptr, pj, D, D, D, D, 0, 0, 0);

    // hidden = relu(pj @ w1T')   [8192][4096]
    gemm_f16<1><<<dim3(NTOK / BM, DFF / BN, 1), blk, 0, stream>>>(
        pj, w1T, nullptr, hd, D, D, D, DFF, 0, 0, 0);

    // out = hd @ w2T' + x   fp32 [8192][1024]
    gemm_f16<3><<<dim3(NTOK / BM, D / BN, 1), blk, 0, stream>>>(
        hd, w2T, x, out, DFF, DFF, DFF, D, 0, 0, 0);
}